// Round 4
// baseline (601.861 us; speedup 1.0000x reference)
//
#include <hip/hip_runtime.h>
#include <hip/hip_bf16.h>
#include <math.h>

#define D_MODEL 768
#define NH 12
#define HD 64
#define BATCH 2
#define SEQ 4096
#define NROWS (BATCH * SEQ)   // 8192

#define QSCALE 0.18033688011112042f   // 0.125 * log2(e): softmax via exp2

typedef __attribute__((ext_vector_type(8))) short short8;
typedef __attribute__((ext_vector_type(4))) short short4v;
typedef __attribute__((ext_vector_type(4))) float f32x4;
typedef __attribute__((ext_vector_type(16))) float f32x16;
typedef __attribute__((ext_vector_type(4))) unsigned int uint4v;

__device__ inline unsigned short f2bf(float f) {
    __hip_bfloat16 h = __float2bfloat16(f);   // RNE
    return *reinterpret_cast<unsigned short*>(&h);
}

// packed f32x2 -> bf16x2 (RNE), one VALU op
__device__ __forceinline__ unsigned int cvtpk_bf16(float lo, float hi) {
    unsigned int d;
    asm("v_cvt_pk_bf16_f32 %0, %1, %2" : "=v"(d) : "v"(lo), "v"(hi));
    return d;
}

__device__ __forceinline__ short8 u4_as_s8(uint4v u) {
    return *reinterpret_cast<short8*>(&u);
}

// async global->LDS DMA, 16 B per lane; LDS dest is wave-uniform base + lane*16
__device__ __forceinline__ void async_ld16(const unsigned short* g, unsigned short* l) {
    __builtin_amdgcn_global_load_lds(
        (const __attribute__((address_space(1))) void*)g,
        (__attribute__((address_space(3))) void*)l, 16, 0, 0);
}

// ---------------------------------------------------------------------------
// x fp32 -> bf16 (same layout). 8 elems/thread.
// ---------------------------------------------------------------------------
__global__ __launch_bounds__(256) void convert_x_k(
    const float* __restrict__ x, unsigned short* __restrict__ xb)
{
    size_t i = ((size_t)blockIdx.x * 256 + threadIdx.x) * 8;
    float4 a = *(const float4*)(x + i);
    float4 b = *(const float4*)(x + i + 4);
    short8 o;
    o[0] = (short)f2bf(a.x); o[1] = (short)f2bf(a.y);
    o[2] = (short)f2bf(a.z); o[3] = (short)f2bf(a.w);
    o[4] = (short)f2bf(b.x); o[5] = (short)f2bf(b.y);
    o[6] = (short)f2bf(b.z); o[7] = (short)f2bf(b.w);
    *(short8*)(xb + i) = o;
}

// ---------------------------------------------------------------------------
// W fp32 [768][768] -> Wt bf16 [768][768] TRANSPOSED (Wt[n][k] = W[k][n]).
// ---------------------------------------------------------------------------
__global__ __launch_bounds__(256) void convert_wt_k(
    const float* __restrict__ Wq, const float* __restrict__ Wk,
    const float* __restrict__ Wv, const float* __restrict__ Wo,
    unsigned short* __restrict__ wt)
{
    const float* W = (blockIdx.z == 0) ? Wq : (blockIdx.z == 1) ? Wk
                   : (blockIdx.z == 2) ? Wv : Wo;
    unsigned short* dst = wt + (size_t)blockIdx.z * D_MODEL * D_MODEL;
    __shared__ float tile[64][65];
    const int k0 = blockIdx.x * 64, n0 = blockIdx.y * 64;
    const int t = threadIdx.x;
    const int r = t >> 2, seg = t & 3;
    const float* src = W + (size_t)(k0 + r) * D_MODEL + n0 + seg * 16;
    #pragma unroll
    for (int i = 0; i < 4; ++i) {
        float4 v = *(const float4*)(src + i * 4);
        tile[r][seg * 16 + i * 4 + 0] = v.x;
        tile[r][seg * 16 + i * 4 + 1] = v.y;
        tile[r][seg * 16 + i * 4 + 2] = v.z;
        tile[r][seg * 16 + i * 4 + 3] = v.w;
    }
    __syncthreads();
    unsigned short* d = dst + (size_t)(n0 + r) * D_MODEL + k0 + seg * 16;
    short8 o0, o1;
    #pragma unroll
    for (int j = 0; j < 8; ++j) o0[j] = (short)f2bf(tile[seg * 16 + j][r]);
    #pragma unroll
    for (int j = 0; j < 8; ++j) o1[j] = (short)f2bf(tile[seg * 16 + 8 + j][r]);
    *(short8*)(d) = o0;
    *(short8*)(d + 8) = o1;
}

// ---------------------------------------------------------------------------
// QKV projection, bf16 MFMA 16x16x32, M=128 x N=64 tile, BK=64 (R1 config).
// ---------------------------------------------------------------------------
__global__ __launch_bounds__(256) void qkv_mfma_k(
    const unsigned short* __restrict__ xb,
    const unsigned short* __restrict__ wt,
    const float* __restrict__ bq, const float* __restrict__ bk,
    const float* __restrict__ bv,
    unsigned short* __restrict__ qb,         // [B,H,S,64] (pre-scaled)
    unsigned short* __restrict__ kb,         // [B,H,S,64]
    unsigned short* __restrict__ vtb)        // [B,H,64,S]
{
    __shared__ unsigned short As[128][64];   // unpadded (DMA-compatible)
    __shared__ unsigned short Bs[64][64];
    const int z = blockIdx.z;
    const unsigned short* Wt = wt + (size_t)z * D_MODEL * D_MODEL;
    const float* bias = (z == 0) ? bq : (z == 1) ? bk : bv;
    const int t = threadIdx.x;
    const int w = t >> 6, lane = t & 63, quad = lane >> 4, col = lane & 15;
    const int r0 = blockIdx.x * 128;
    const int c0 = blockIdx.y * 64;

    f32x4 acc[2][4] = {};

    for (int kk = 0; kk < D_MODEL; kk += 64) {
        __syncthreads();   // prior compute done reading LDS
        #pragma unroll
        for (int j = 0; j < 4; ++j) {
            int c = (w * 4 + j) * 64 + lane;
            async_ld16(xb + (size_t)(r0 + (c >> 3)) * D_MODEL + kk + (c & 7) * 8,
                       &As[0][0] + (size_t)c * 8);
        }
        #pragma unroll
        for (int j = 0; j < 2; ++j) {
            int c = (w * 2 + j) * 64 + lane;
            async_ld16(Wt + (size_t)(c0 + (c >> 3)) * D_MODEL + kk + (c & 7) * 8,
                       &Bs[0][0] + (size_t)c * 8);
        }
        __syncthreads();   // DMA drained by pre-barrier vmcnt(0)
        #pragma unroll
        for (int ks = 0; ks < 2; ++ks) {
            short8 af[2], bf[4];
            af[0] = *(const short8*)&As[w * 32 + col][ks * 32 + quad * 8];
            af[1] = *(const short8*)&As[w * 32 + 16 + col][ks * 32 + quad * 8];
            #pragma unroll
            for (int nt = 0; nt < 4; ++nt)
                bf[nt] = *(const short8*)&Bs[nt * 16 + col][ks * 32 + quad * 8];
            #pragma unroll
            for (int mt = 0; mt < 2; ++mt)
                #pragma unroll
                for (int nt = 0; nt < 4; ++nt)
                    acc[mt][nt] = __builtin_amdgcn_mfma_f32_16x16x32_bf16(
                        af[mt], bf[nt], acc[mt][nt], 0, 0, 0);
        }
    }

    const int h = blockIdx.y;
    #pragma unroll
    for (int nt = 0; nt < 4; ++nt) {
        const float bv_ = bias[c0 + nt * 16 + col];
        const int hd = nt * 16 + col;
        #pragma unroll
        for (int mt = 0; mt < 2; ++mt) {
            #pragma unroll
            for (int reg = 0; reg < 4; ++reg) {
                int r = r0 + w * 32 + mt * 16 + quad * 4 + reg;
                int b = r >> 12, s = r & (SEQ - 1);
                float val = acc[mt][nt][reg] + bv_;
                size_t bh = (size_t)(b * NH + h);
                if (z == 0)
                    qb[(bh * SEQ + s) * HD + hd] = f2bf(val * QSCALE);
                else if (z == 1)
                    kb[(bh * SEQ + s) * HD + hd] = f2bf(val);
                else
                    vtb[(bh * HD + hd) * SEQ + s] = f2bf(val);
            }
        }
    }
}

// ---------------------------------------------------------------------------
// Output projection: out = ab @ Wo + bo, fp32 out. (R1 config.)
// ---------------------------------------------------------------------------
__global__ __launch_bounds__(256) void out_mfma_k(
    const unsigned short* __restrict__ ab,
    const unsigned short* __restrict__ wot,
    const float* __restrict__ bo,
    float* __restrict__ out)
{
    __shared__ unsigned short As[128][64];
    __shared__ unsigned short Bs[64][64];
    const int t = threadIdx.x;
    const int w = t >> 6, lane = t & 63, quad = lane >> 4, col = lane & 15;
    const int r0 = blockIdx.x * 128;
    const int c0 = blockIdx.y * 64;

    f32x4 acc[2][4] = {};

    for (int kk = 0; kk < D_MODEL; kk += 64) {
        __syncthreads();
        #pragma unroll
        for (int j = 0; j < 4; ++j) {
            int c = (w * 4 + j) * 64 + lane;
            async_ld16(ab + (size_t)(r0 + (c >> 3)) * D_MODEL + kk + (c & 7) * 8,
                       &As[0][0] + (size_t)c * 8);
        }
        #pragma unroll
        for (int j = 0; j < 2; ++j) {
            int c = (w * 2 + j) * 64 + lane;
            async_ld16(wot + (size_t)(c0 + (c >> 3)) * D_MODEL + kk + (c & 7) * 8,
                       &Bs[0][0] + (size_t)c * 8);
        }
        __syncthreads();
        #pragma unroll
        for (int ks = 0; ks < 2; ++ks) {
            short8 af[2], bf[4];
            af[0] = *(const short8*)&As[w * 32 + col][ks * 32 + quad * 8];
            af[1] = *(const short8*)&As[w * 32 + 16 + col][ks * 32 + quad * 8];
            #pragma unroll
            for (int nt = 0; nt < 4; ++nt)
                bf[nt] = *(const short8*)&Bs[nt * 16 + col][ks * 32 + quad * 8];
            #pragma unroll
            for (int mt = 0; mt < 2; ++mt)
                #pragma unroll
                for (int nt = 0; nt < 4; ++nt)
                    acc[mt][nt] = __builtin_amdgcn_mfma_f32_16x16x32_bf16(
                        af[mt], bf[nt], acc[mt][nt], 0, 0, 0);
        }
    }

    #pragma unroll
    for (int nt = 0; nt < 4; ++nt) {
        const float bv_ = bo[c0 + nt * 16 + col];
        #pragma unroll
        for (int mt = 0; mt < 2; ++mt) {
            #pragma unroll
            for (int reg = 0; reg < 4; ++reg) {
                int r = r0 + w * 32 + mt * 16 + quad * 4 + reg;
                out[(size_t)r * D_MODEL + c0 + nt * 16 + col] = acc[mt][nt][reg] + bv_;
            }
        }
    }
}

// ---------------------------------------------------------------------------
// Shared inner machinery for flash kernels (R1 structure, 4 waves x 32 q).
// ---------------------------------------------------------------------------
__device__ __forceinline__ void softmax_pack(
    const f32x16& s, float& lsum, short8& pf0, short8& pf1)
{
    float p[16];
    #pragma unroll
    for (int r = 0; r < 16; ++r)
        p[r] = __builtin_amdgcn_exp2f(s[r]);
    lsum += (((p[0] + p[1]) + (p[2] + p[3])) + ((p[4] + p[5]) + (p[6] + p[7])))
          + (((p[8] + p[9]) + (p[10] + p[11])) + ((p[12] + p[13]) + (p[14] + p[15])));
    unsigned int c01 = cvtpk_bf16(p[0],  p[1]);
    unsigned int c45 = cvtpk_bf16(p[4],  p[5]);
    unsigned int c23 = cvtpk_bf16(p[2],  p[3]);
    unsigned int c67 = cvtpk_bf16(p[6],  p[7]);
    unsigned int c89 = cvtpk_bf16(p[8],  p[9]);
    unsigned int cCD = cvtpk_bf16(p[12], p[13]);
    unsigned int cAB = cvtpk_bf16(p[10], p[11]);
    unsigned int cEF = cvtpk_bf16(p[14], p[15]);
    auto r0 = __builtin_amdgcn_permlane32_swap((int)c01, (int)c45, false, false);
    auto r1 = __builtin_amdgcn_permlane32_swap((int)c23, (int)c67, false, false);
    auto r2 = __builtin_amdgcn_permlane32_swap((int)c89, (int)cCD, false, false);
    auto r3 = __builtin_amdgcn_permlane32_swap((int)cAB, (int)cEF, false, false);
    uint4v u0, u1;
    u0[0] = (unsigned int)r0[0]; u0[1] = (unsigned int)r1[0];
    u0[2] = (unsigned int)r0[1]; u0[3] = (unsigned int)r1[1];
    u1[0] = (unsigned int)r2[0]; u1[1] = (unsigned int)r3[0];
    u1[2] = (unsigned int)r2[1]; u1[3] = (unsigned int)r3[1];
    pf0 = u4_as_s8(u0);
    pf1 = u4_as_s8(u1);
}

// Core flash loop over keys [kt0, kt0+nk): computes oacc (O^T frags) + lsum.
// Same per-wave structure as R1 (measured 137 us at grid 768).
__device__ __forceinline__ void flash_core(
    const unsigned short* __restrict__ qg,
    const unsigned short* __restrict__ kg,
    const unsigned short* __restrict__ vg,
    int q0, int kt0, int nk, int w, int lane,
    unsigned short (*Ks)[66], unsigned short (*Vts)[66],
    f32x16 oacc[2], float& lsum)
{
    const int l31 = lane & 31, hi = lane >> 5;
    // persistent Q B-frags: q(n) = q0 + w*32 + l31, hd(k) = ks*16 + hi*8 + j
    short8 qf[4];
    {
        const unsigned short* src = qg + (size_t)(q0 + w * 32 + l31) * HD + hi * 8;
        #pragma unroll
        for (int ks = 0; ks < 4; ++ks)
            qf[ks] = *(const short8*)(src + ks * 16);
    }

    const int srow = lane, sseg = w;
    // prologue prefetch: tile kt0
    short8 kr0, kr1, vr0, vr1;
    {
        const unsigned short* kp = kg + (size_t)(kt0 + srow) * HD + sseg * 16;
        kr0 = *(const short8*)(kp);
        kr1 = *(const short8*)(kp + 8);
        const unsigned short* vp = vg + (size_t)srow * SEQ + kt0 + sseg * 16;
        vr0 = *(const short8*)(vp);
        vr1 = *(const short8*)(vp + 8);
    }

    for (int kt = kt0; kt < kt0 + nk; kt += 64) {
        __syncthreads();   // prior compute done reading LDS
        *(short8*)&Ks[srow][sseg * 16]      = kr0;
        *(short8*)&Ks[srow][sseg * 16 + 8]  = kr1;
        *(short8*)&Vts[srow][sseg * 16]     = vr0;
        *(short8*)&Vts[srow][sseg * 16 + 8] = vr1;
        // T14: issue next tile's loads now; latency hides under compute below
        if (kt + 64 < kt0 + nk) {
            const unsigned short* kp = kg + (size_t)(kt + 64 + srow) * HD + sseg * 16;
            kr0 = *(const short8*)(kp);
            kr1 = *(const short8*)(kp + 8);
            const unsigned short* vp = vg + (size_t)srow * SEQ + kt + 64 + sseg * 16;
            vr0 = *(const short8*)(vp);
            vr1 = *(const short8*)(vp + 8);
        }
        __syncthreads();   // staged tile visible to all waves

        // S^T = K Q^T, one 32x32 tile per kti; softmax + in-register P pack
        short8 pf[4];
        #pragma unroll
        for (int kti = 0; kti < 2; ++kti) {
            f32x16 s = {};
            __builtin_amdgcn_s_setprio(1);
            #pragma unroll
            for (int ks = 0; ks < 4; ++ks) {
                short8 kf = *(const short8*)&Ks[kti * 32 + l31][ks * 16 + hi * 8];
                s = __builtin_amdgcn_mfma_f32_32x32x16_bf16(kf, qf[ks], s, 0, 0, 0);
            }
            __builtin_amdgcn_s_setprio(0);
            softmax_pack(s, lsum, pf[kti * 2 + 0], pf[kti * 2 + 1]);
        }

        // PV: O^T = V^T P   (A = V^T frag from LDS, B = P frag in registers)
        __builtin_amdgcn_s_setprio(1);
        #pragma unroll
        for (int ks = 0; ks < 4; ++ks) {
            short8 pfk = pf[ks];
            #pragma unroll
            for (int dt = 0; dt < 2; ++dt) {
                short8 vf = *(const short8*)&Vts[dt * 32 + l31][ks * 16 + hi * 8];
                oacc[dt] = __builtin_amdgcn_mfma_f32_32x32x16_bf16(
                    vf, pfk, oacc[dt], 0, 0, 0);
            }
        }
        __builtin_amdgcn_s_setprio(0);
    }
}

// ---------------------------------------------------------------------------
// Split-K flash (R10): grid (SEQ/128, NH, BATCH*2) = 1536 blocks -> 6 blocks
// per CU x 4 waves = 24 waves/CU (vs 12 grid-capped before). Each block sweeps
// HALF the keys; fixed-max softmax makes the merge exact pure sums:
// O = O1 + O2, l = l1 + l2. Partial O (f32) + l written to workspace;
// combine_k normalizes and emits ab bf16.
// ---------------------------------------------------------------------------
__global__ __launch_bounds__(256) void flash_split_k(
    const unsigned short* __restrict__ qb,
    const unsigned short* __restrict__ kb,
    const unsigned short* __restrict__ vtb,
    float* __restrict__ opart,               // [2][B*NH*SEQ][64] f32
    float* __restrict__ lpart)               // [2][B*NH*SEQ] f32
{
    __shared__ unsigned short Ks[64][66];
    __shared__ unsigned short Vts[64][66];

    const int t = threadIdx.x;
    const int w = t >> 6, lane = t & 63;
    const int l31 = lane & 31, hi = lane >> 5;
    const int q0 = blockIdx.x * 128;
    const int h = blockIdx.y;
    const int b = blockIdx.z >> 1, half = blockIdx.z & 1;
    const size_t bh = (size_t)b * NH + h;
    const unsigned short* qg = qb + bh * SEQ * HD;
    const unsigned short* kg = kb + bh * SEQ * HD;
    const unsigned short* vg = vtb + bh * HD * SEQ;

    f32x16 oacc[2] = {};
    float lsum = 0.f;
    flash_core(qg, kg, vg, q0, half * (SEQ / 2), SEQ / 2, w, lane, Ks, Vts,
               oacc, lsum);

    // epilogue: write f32 partials (no normalize)
    lsum += __shfl_xor(lsum, 32);
    const size_t row = bh * SEQ + (q0 + w * 32 + l31);
    float* ob = opart + ((size_t)half * NROWS * NH * 0 /*see layout*/
                         + (size_t)half * (size_t)BATCH * NH * SEQ * HD)
                      + row * HD;
    if (hi == 0) lpart[(size_t)half * BATCH * NH * SEQ + row] = lsum;
    #pragma unroll
    for (int dt = 0; dt < 2; ++dt) {
        #pragma unroll
        for (int rq = 0; rq < 4; ++rq) {
            f32x4 v;
            v[0] = oacc[dt][rq * 4 + 0];
            v[1] = oacc[dt][rq * 4 + 1];
            v[2] = oacc[dt][rq * 4 + 2];
            v[3] = oacc[dt][rq * 4 + 3];
            *(f32x4*)(ob + dt * 32 + rq * 8 + hi * 4) = v;
        }
    }
}

// combine: ab[b][s][h*64+d] = bf16((O1+O2) / (l1+l2)); 8 elems/thread.
__global__ __launch_bounds__(256) void combine_k(
    const float* __restrict__ opart, const float* __restrict__ lpart,
    unsigned short* __restrict__ ab)
{
    const size_t nO = (size_t)BATCH * NH * SEQ * HD;
    size_t e = ((size_t)blockIdx.x * 256 + threadIdx.x) * 8;
    size_t row = e >> 6;          // bh*SEQ + s
    int d0 = (int)(e & 63);
    int bh = (int)(row >> 12), s = (int)(row & (SEQ - 1));
    int b = bh / NH, h = bh - b * NH;
    float inv = 1.0f / (lpart[row] + lpart[(size_t)BATCH * NH * SEQ + row]);
    f32x4 a0 = *(const f32x4*)(opart + e);
    f32x4 a1 = *(const f32x4*)(opart + e + 4);
    f32x4 b0 = *(const f32x4*)(opart + nO + e);
    f32x4 b1 = *(const f32x4*)(opart + nO + e + 4);
    short8 o;
    #pragma unroll
    for (int j = 0; j < 4; ++j) {
        o[j]     = (short)f2bf((a0[j] + b0[j]) * inv);
        o[4 + j] = (short)f2bf((a1[j] + b1[j]) * inv);
    }
    *(short8*)(ab + ((size_t)(b * SEQ + s)) * D_MODEL + h * HD + d0) = o;
}

// ---------------------------------------------------------------------------
// Fallback: R1 flash (measured 137 us) — used only if workspace is too small
// for split-K partials.
// ---------------------------------------------------------------------------
__global__ __launch_bounds__(256) void flash_mfma_k(
    const unsigned short* __restrict__ qb,
    const unsigned short* __restrict__ kb,
    const unsigned short* __restrict__ vtb,
    unsigned short* __restrict__ ab)
{
    __shared__ unsigned short Ks[64][66];
    __shared__ unsigned short Vts[64][66];

    const int t = threadIdx.x;
    const int w = t >> 6, lane = t & 63;
    const int l31 = lane & 31, hi = lane >> 5;
    const int q0 = blockIdx.x * 128;
    const int h = blockIdx.y, b = blockIdx.z;
    const size_t bh = (size_t)b * NH + h;
    const unsigned short* qg = qb + bh * SEQ * HD;
    const unsigned short* kg = kb + bh * SEQ * HD;
    const unsigned short* vg = vtb + bh * HD * SEQ;

    f32x16 oacc[2] = {};
    float lsum = 0.f;
    flash_core(qg, kg, vg, q0, 0, SEQ, w, lane, Ks, Vts, oacc, lsum);

    lsum += __shfl_xor(lsum, 32);
    float inv = 1.0f / lsum;
    int s = q0 + w * 32 + l31;
    unsigned short* dst = ab + ((size_t)b * SEQ + s) * D_MODEL + h * HD;
    #pragma unroll
    for (int dt = 0; dt < 2; ++dt) {
        #pragma unroll
        for (int rq = 0; rq < 4; ++rq) {
            short4v o4;
            o4[0] = (short)f2bf(oacc[dt][rq * 4 + 0] * inv);
            o4[1] = (short)f2bf(oacc[dt][rq * 4 + 1] * inv);
            o4[2] = (short)f2bf(oacc[dt][rq * 4 + 2] * inv);
            o4[3] = (short)f2bf(oacc[dt][rq * 4 + 3] * inv);
            *(short4v*)(dst + dt * 32 + rq * 8 + hi * 4) = o4;
        }
    }
}

extern "C" void kernel_launch(void* const* d_in, const int* in_sizes, int n_in,
                              void* d_out, int out_size, void* d_ws, size_t ws_size,
                              hipStream_t stream)
{
    const float* x  = (const float*)d_in[0];
    const float* Wq = (const float*)d_in[1];
    const float* bq = (const float*)d_in[2];
    const float* Wk = (const float*)d_in[3];
    const float* bk = (const float*)d_in[4];
    const float* Wv = (const float*)d_in[5];
    const float* bv = (const float*)d_in[6];
    const float* Wo = (const float*)d_in[7];
    const float* bo = (const float*)d_in[8];
    float* out = (float*)d_out;

    const size_t n_x  = (size_t)NROWS * D_MODEL;       // 6.29M (== B*H*S*HD)
    const size_t n_w  = (size_t)D_MODEL * D_MODEL;
    const size_t n_l  = (size_t)BATCH * NH * SEQ;      // 98304
    unsigned short* xb  = (unsigned short*)d_ws;
    unsigned short* wt  = xb + n_x;
    unsigned short* qb  = wt + 4 * n_w;
    unsigned short* kb  = qb + n_x;
    unsigned short* vtb = kb + n_x;
    unsigned short* ab  = vtb + n_x;
    float* opart = (float*)(ab + n_x);                 // [2][n_x] f32
    float* lpart = opart + 2 * n_x;                    // [2][n_l] f32
    const size_t need = ((size_t)5 * n_x + 4 * n_w) * sizeof(unsigned short);
    const size_t need_split = need + (2 * n_x + 2 * n_l) * sizeof(float);
    if (ws_size < need) return;

    convert_x_k<<<dim3((int)(n_x / 2048)), 256, 0, stream>>>(x, xb);
    convert_wt_k<<<dim3(12, 12, 4), 256, 0, stream>>>(Wq, Wk, Wv, Wo, wt);
    qkv_mfma_k<<<dim3(NROWS / 128, D_MODEL / 64, 3), 256, 0, stream>>>(
        xb, wt, bq, bk, bv, qb, kb, vtb);
    if (ws_size >= need_split) {
        flash_split_k<<<dim3(SEQ / 128, NH, BATCH * 2), 256, 0, stream>>>(
            qb, kb, vtb, opart, lpart);
        combine_k<<<dim3((int)(n_x / 2048)), 256, 0, stream>>>(opart, lpart, ab);
    } else {
        flash_mfma_k<<<dim3(SEQ / 128, NH, BATCH), 256, 0, stream>>>(
            qb, kb, vtb, ab);
    }
    out_mfma_k<<<dim3(NROWS / 128, D_MODEL / 64), 256, 0, stream>>>(
        ab, wt + 3 * n_w, bo, out);
}

// Round 5
// 315.289 us; speedup vs baseline: 1.9089x; 1.9089x over previous
//
#include <hip/hip_runtime.h>
#include <hip/hip_bf16.h>
#include <math.h>

#define D_MODEL 768
#define NH 12
#define HD 64
#define BATCH 2
#define SEQ 4096
#define NROWS (BATCH * SEQ)   // 8192

#define QSCALE 0.18033688011112042f   // 0.125 * log2(e): softmax via exp2

typedef __attribute__((ext_vector_type(8))) short short8;
typedef __attribute__((ext_vector_type(4))) short short4v;
typedef __attribute__((ext_vector_type(4))) float f32x4;
typedef __attribute__((ext_vector_type(16))) float f32x16;
typedef __attribute__((ext_vector_type(4))) unsigned int uint4v;

__device__ inline unsigned short f2bf(float f) {
    __hip_bfloat16 h = __float2bfloat16(f);   // RNE
    return *reinterpret_cast<unsigned short*>(&h);
}

// packed f32x2 -> bf16x2 (RNE), one VALU op
__device__ __forceinline__ unsigned int cvtpk_bf16(float lo, float hi) {
    unsigned int d;
    asm("v_cvt_pk_bf16_f32 %0, %1, %2" : "=v"(d) : "v"(lo), "v"(hi));
    return d;
}

__device__ __forceinline__ short8 u4_as_s8(uint4v u) {
    return *reinterpret_cast<short8*>(&u);
}

// async global->LDS DMA, 16 B per lane; LDS dest is wave-uniform base + lane*16
__device__ __forceinline__ void async_ld16(const unsigned short* g, unsigned short* l) {
    __builtin_amdgcn_global_load_lds(
        (const __attribute__((address_space(1))) void*)g,
        (__attribute__((address_space(3))) void*)l, 16, 0, 0);
}

// ---------------------------------------------------------------------------
// x fp32 -> bf16 (same layout). 8 elems/thread.
// ---------------------------------------------------------------------------
__global__ __launch_bounds__(256) void convert_x_k(
    const float* __restrict__ x, unsigned short* __restrict__ xb)
{
    size_t i = ((size_t)blockIdx.x * 256 + threadIdx.x) * 8;
    float4 a = *(const float4*)(x + i);
    float4 b = *(const float4*)(x + i + 4);
    short8 o;
    o[0] = (short)f2bf(a.x); o[1] = (short)f2bf(a.y);
    o[2] = (short)f2bf(a.z); o[3] = (short)f2bf(a.w);
    o[4] = (short)f2bf(b.x); o[5] = (short)f2bf(b.y);
    o[6] = (short)f2bf(b.z); o[7] = (short)f2bf(b.w);
    *(short8*)(xb + i) = o;
}

// ---------------------------------------------------------------------------
// W fp32 [768][768] -> Wt bf16 [768][768] TRANSPOSED (Wt[n][k] = W[k][n]).
// ---------------------------------------------------------------------------
__global__ __launch_bounds__(256) void convert_wt_k(
    const float* __restrict__ Wq, const float* __restrict__ Wk,
    const float* __restrict__ Wv, const float* __restrict__ Wo,
    unsigned short* __restrict__ wt)
{
    const float* W = (blockIdx.z == 0) ? Wq : (blockIdx.z == 1) ? Wk
                   : (blockIdx.z == 2) ? Wv : Wo;
    unsigned short* dst = wt + (size_t)blockIdx.z * D_MODEL * D_MODEL;
    __shared__ float tile[64][65];
    const int k0 = blockIdx.x * 64, n0 = blockIdx.y * 64;
    const int t = threadIdx.x;
    const int r = t >> 2, seg = t & 3;
    const float* src = W + (size_t)(k0 + r) * D_MODEL + n0 + seg * 16;
    #pragma unroll
    for (int i = 0; i < 4; ++i) {
        float4 v = *(const float4*)(src + i * 4);
        tile[r][seg * 16 + i * 4 + 0] = v.x;
        tile[r][seg * 16 + i * 4 + 1] = v.y;
        tile[r][seg * 16 + i * 4 + 2] = v.z;
        tile[r][seg * 16 + i * 4 + 3] = v.w;
    }
    __syncthreads();
    unsigned short* d = dst + (size_t)(n0 + r) * D_MODEL + k0 + seg * 16;
    short8 o0, o1;
    #pragma unroll
    for (int j = 0; j < 8; ++j) o0[j] = (short)f2bf(tile[seg * 16 + j][r]);
    #pragma unroll
    for (int j = 0; j < 8; ++j) o1[j] = (short)f2bf(tile[seg * 16 + 8 + j][r]);
    *(short8*)(d) = o0;
    *(short8*)(d + 8) = o1;
}

// ---------------------------------------------------------------------------
// QKV projection, bf16 MFMA 16x16x32, M=128 x N=64 tile, BK=64 (R1 config).
// ---------------------------------------------------------------------------
__global__ __launch_bounds__(256) void qkv_mfma_k(
    const unsigned short* __restrict__ xb,
    const unsigned short* __restrict__ wt,
    const float* __restrict__ bq, const float* __restrict__ bk,
    const float* __restrict__ bv,
    unsigned short* __restrict__ qb,         // [B,H,S,64] (pre-scaled)
    unsigned short* __restrict__ kb,         // [B,H,S,64]
    unsigned short* __restrict__ vtb)        // [B,H,64,S]
{
    __shared__ unsigned short As[128][64];   // unpadded (DMA-compatible)
    __shared__ unsigned short Bs[64][64];
    const int z = blockIdx.z;
    const unsigned short* Wt = wt + (size_t)z * D_MODEL * D_MODEL;
    const float* bias = (z == 0) ? bq : (z == 1) ? bk : bv;
    const int t = threadIdx.x;
    const int w = t >> 6, lane = t & 63, quad = lane >> 4, col = lane & 15;
    const int r0 = blockIdx.x * 128;
    const int c0 = blockIdx.y * 64;

    f32x4 acc[2][4] = {};

    for (int kk = 0; kk < D_MODEL; kk += 64) {
        __syncthreads();   // prior compute done reading LDS
        #pragma unroll
        for (int j = 0; j < 4; ++j) {
            int c = (w * 4 + j) * 64 + lane;
            async_ld16(xb + (size_t)(r0 + (c >> 3)) * D_MODEL + kk + (c & 7) * 8,
                       &As[0][0] + (size_t)c * 8);
        }
        #pragma unroll
        for (int j = 0; j < 2; ++j) {
            int c = (w * 2 + j) * 64 + lane;
            async_ld16(Wt + (size_t)(c0 + (c >> 3)) * D_MODEL + kk + (c & 7) * 8,
                       &Bs[0][0] + (size_t)c * 8);
        }
        __syncthreads();   // DMA drained by pre-barrier vmcnt(0)
        #pragma unroll
        for (int ks = 0; ks < 2; ++ks) {
            short8 af[2], bf[4];
            af[0] = *(const short8*)&As[w * 32 + col][ks * 32 + quad * 8];
            af[1] = *(const short8*)&As[w * 32 + 16 + col][ks * 32 + quad * 8];
            #pragma unroll
            for (int nt = 0; nt < 4; ++nt)
                bf[nt] = *(const short8*)&Bs[nt * 16 + col][ks * 32 + quad * 8];
            #pragma unroll
            for (int mt = 0; mt < 2; ++mt)
                #pragma unroll
                for (int nt = 0; nt < 4; ++nt)
                    acc[mt][nt] = __builtin_amdgcn_mfma_f32_16x16x32_bf16(
                        af[mt], bf[nt], acc[mt][nt], 0, 0, 0);
        }
    }

    const int h = blockIdx.y;
    #pragma unroll
    for (int nt = 0; nt < 4; ++nt) {
        const float bv_ = bias[c0 + nt * 16 + col];
        const int hd = nt * 16 + col;
        #pragma unroll
        for (int mt = 0; mt < 2; ++mt) {
            #pragma unroll
            for (int reg = 0; reg < 4; ++reg) {
                int r = r0 + w * 32 + mt * 16 + quad * 4 + reg;
                int b = r >> 12, s = r & (SEQ - 1);
                float val = acc[mt][nt][reg] + bv_;
                size_t bh = (size_t)(b * NH + h);
                if (z == 0)
                    qb[(bh * SEQ + s) * HD + hd] = f2bf(val * QSCALE);
                else if (z == 1)
                    kb[(bh * SEQ + s) * HD + hd] = f2bf(val);
                else
                    vtb[(bh * HD + hd) * SEQ + s] = f2bf(val);
            }
        }
    }
}

// ---------------------------------------------------------------------------
// Output projection: out = ab @ Wo + bo, fp32 out. (R1 config.)
// ---------------------------------------------------------------------------
__global__ __launch_bounds__(256) void out_mfma_k(
    const unsigned short* __restrict__ ab,
    const unsigned short* __restrict__ wot,
    const float* __restrict__ bo,
    float* __restrict__ out)
{
    __shared__ unsigned short As[128][64];
    __shared__ unsigned short Bs[64][64];
    const int t = threadIdx.x;
    const int w = t >> 6, lane = t & 63, quad = lane >> 4, col = lane & 15;
    const int r0 = blockIdx.x * 128;
    const int c0 = blockIdx.y * 64;

    f32x4 acc[2][4] = {};

    for (int kk = 0; kk < D_MODEL; kk += 64) {
        __syncthreads();
        #pragma unroll
        for (int j = 0; j < 4; ++j) {
            int c = (w * 4 + j) * 64 + lane;
            async_ld16(ab + (size_t)(r0 + (c >> 3)) * D_MODEL + kk + (c & 7) * 8,
                       &As[0][0] + (size_t)c * 8);
        }
        #pragma unroll
        for (int j = 0; j < 2; ++j) {
            int c = (w * 2 + j) * 64 + lane;
            async_ld16(wot + (size_t)(c0 + (c >> 3)) * D_MODEL + kk + (c & 7) * 8,
                       &Bs[0][0] + (size_t)c * 8);
        }
        __syncthreads();
        #pragma unroll
        for (int ks = 0; ks < 2; ++ks) {
            short8 af[2], bf[4];
            af[0] = *(const short8*)&As[w * 32 + col][ks * 32 + quad * 8];
            af[1] = *(const short8*)&As[w * 32 + 16 + col][ks * 32 + quad * 8];
            #pragma unroll
            for (int nt = 0; nt < 4; ++nt)
                bf[nt] = *(const short8*)&Bs[nt * 16 + col][ks * 32 + quad * 8];
            #pragma unroll
            for (int mt = 0; mt < 2; ++mt)
                #pragma unroll
                for (int nt = 0; nt < 4; ++nt)
                    acc[mt][nt] = __builtin_amdgcn_mfma_f32_16x16x32_bf16(
                        af[mt], bf[nt], acc[mt][nt], 0, 0, 0);
        }
    }

    #pragma unroll
    for (int nt = 0; nt < 4; ++nt) {
        const float bv_ = bo[c0 + nt * 16 + col];
        #pragma unroll
        for (int mt = 0; mt < 2; ++mt) {
            #pragma unroll
            for (int reg = 0; reg < 4; ++reg) {
                int r = r0 + w * 32 + mt * 16 + quad * 4 + reg;
                out[(size_t)r * D_MODEL + c0 + nt * 16 + col] = acc[mt][nt][reg] + bv_;
            }
        }
    }
}

// register-only helper (proven safe in R3: no LDS params)
__device__ __forceinline__ void softmax_pack(
    const f32x16& s, float& lsum, short8& pf0, short8& pf1)
{
    float p[16];
    #pragma unroll
    for (int r = 0; r < 16; ++r)
        p[r] = __builtin_amdgcn_exp2f(s[r]);
    lsum += (((p[0] + p[1]) + (p[2] + p[3])) + ((p[4] + p[5]) + (p[6] + p[7])))
          + (((p[8] + p[9]) + (p[10] + p[11])) + ((p[12] + p[13]) + (p[14] + p[15])));
    unsigned int c01 = cvtpk_bf16(p[0],  p[1]);
    unsigned int c45 = cvtpk_bf16(p[4],  p[5]);
    unsigned int c23 = cvtpk_bf16(p[2],  p[3]);
    unsigned int c67 = cvtpk_bf16(p[6],  p[7]);
    unsigned int c89 = cvtpk_bf16(p[8],  p[9]);
    unsigned int cCD = cvtpk_bf16(p[12], p[13]);
    unsigned int cAB = cvtpk_bf16(p[10], p[11]);
    unsigned int cEF = cvtpk_bf16(p[14], p[15]);
    auto r0 = __builtin_amdgcn_permlane32_swap((int)c01, (int)c45, false, false);
    auto r1 = __builtin_amdgcn_permlane32_swap((int)c23, (int)c67, false, false);
    auto r2 = __builtin_amdgcn_permlane32_swap((int)c89, (int)cCD, false, false);
    auto r3 = __builtin_amdgcn_permlane32_swap((int)cAB, (int)cEF, false, false);
    uint4v u0, u1;
    u0[0] = (unsigned int)r0[0]; u0[1] = (unsigned int)r1[0];
    u0[2] = (unsigned int)r0[1]; u0[3] = (unsigned int)r1[1];
    u1[0] = (unsigned int)r2[0]; u1[1] = (unsigned int)r3[0];
    u1[2] = (unsigned int)r2[1]; u1[3] = (unsigned int)r3[1];
    pf0 = u4_as_s8(u0);
    pf1 = u4_as_s8(u1);
}

// ---------------------------------------------------------------------------
// Split-K flash, R11: EXACT R1 kernel body (LDS used directly at kernel
// scope — R4's LDS-via-function-param collapsed to flat ops, 3x slower),
// with each block sweeping HALF the keys (kt0 = half*2048). Fixed-max
// softmax makes the merge exact pure sums: O = O1+O2, l = l1+l2.
// Grid (SEQ/128, NH, BATCH*2) = 1536 blocks -> 6 blocks/CU x 4 waves
// = 24 waves/CU (vs 12 grid-capped in R1).
// ---------------------------------------------------------------------------
__global__ __launch_bounds__(256) void flash_split_k(
    const unsigned short* __restrict__ qb,   // [B*NH][SEQ][64], pre-scaled
    const unsigned short* __restrict__ kb,   // [B*NH][SEQ][64]
    const unsigned short* __restrict__ vtb,  // [B*NH][64][SEQ]
    float* __restrict__ opart,               // [2][B*NH*SEQ][64] f32
    float* __restrict__ lpart)               // [2][B*NH*SEQ] f32
{
    __shared__ unsigned short Ks[64][66];
    __shared__ unsigned short Vts[64][66];

    const int t = threadIdx.x;
    const int w = t >> 6, lane = t & 63;
    const int l31 = lane & 31, hi = lane >> 5;
    const int q0 = blockIdx.x * 128;
    const int h = blockIdx.y;
    const int b = blockIdx.z >> 1, half = blockIdx.z & 1;
    const int kt0 = half * (SEQ / 2), ktend = kt0 + SEQ / 2;
    const size_t bh = (size_t)b * NH + h;
    const unsigned short* qg = qb + bh * SEQ * HD;
    const unsigned short* kg = kb + bh * SEQ * HD;
    const unsigned short* vg = vtb + bh * HD * SEQ;

    // persistent Q B-frags: q(n) = q0 + w*32 + l31, hd(k) = ks*16 + hi*8 + j
    short8 qf[4];
    {
        const unsigned short* src = qg + (size_t)(q0 + w * 32 + l31) * HD + hi * 8;
        #pragma unroll
        for (int ks = 0; ks < 4; ++ks)
            qf[ks] = *(const short8*)(src + ks * 16);
    }

    f32x16 oacc[2] = {};   // O^T [dt]: d = dt*32+(reg&3)+8*(reg>>2)+4*hi, q = l31
    float lsum = 0.f;
    const int srow = lane, sseg = w;

    // prologue prefetch: tile kt0
    short8 kr0, kr1, vr0, vr1;
    {
        const unsigned short* kp = kg + (size_t)(kt0 + srow) * HD + sseg * 16;
        kr0 = *(const short8*)(kp);
        kr1 = *(const short8*)(kp + 8);
        const unsigned short* vp = vg + (size_t)srow * SEQ + kt0 + sseg * 16;
        vr0 = *(const short8*)(vp);
        vr1 = *(const short8*)(vp + 8);
    }

    for (int kt = kt0; kt < ktend; kt += 64) {
        __syncthreads();   // prior compute done reading LDS
        *(short8*)&Ks[srow][sseg * 16]      = kr0;
        *(short8*)&Ks[srow][sseg * 16 + 8]  = kr1;
        *(short8*)&Vts[srow][sseg * 16]     = vr0;
        *(short8*)&Vts[srow][sseg * 16 + 8] = vr1;
        // T14: issue next tile's loads now; latency hides under compute below
        if (kt + 64 < ktend) {
            const unsigned short* kp = kg + (size_t)(kt + 64 + srow) * HD + sseg * 16;
            kr0 = *(const short8*)(kp);
            kr1 = *(const short8*)(kp + 8);
            const unsigned short* vp = vg + (size_t)srow * SEQ + kt + 64 + sseg * 16;
            vr0 = *(const short8*)(vp);
            vr1 = *(const short8*)(vp + 8);
        }
        __syncthreads();   // staged tile visible to all waves

        // S^T = K Q^T, one 32x32 tile per kti; softmax + in-register P pack
        short8 pf[4];
        #pragma unroll
        for (int kti = 0; kti < 2; ++kti) {
            f32x16 s = {};
            __builtin_amdgcn_s_setprio(1);
            #pragma unroll
            for (int ks = 0; ks < 4; ++ks) {
                short8 kf = *(const short8*)&Ks[kti * 32 + l31][ks * 16 + hi * 8];
                s = __builtin_amdgcn_mfma_f32_32x32x16_bf16(kf, qf[ks], s, 0, 0, 0);
            }
            __builtin_amdgcn_s_setprio(0);
            softmax_pack(s, lsum, pf[kti * 2 + 0], pf[kti * 2 + 1]);
        }

        // PV: O^T = V^T P   (A = V^T frag from LDS, B = P frag in registers)
        __builtin_amdgcn_s_setprio(1);
        #pragma unroll
        for (int ks = 0; ks < 4; ++ks) {
            short8 pfk = pf[ks];
            #pragma unroll
            for (int dt = 0; dt < 2; ++dt) {
                short8 vf = *(const short8*)&Vts[dt * 32 + l31][ks * 16 + hi * 8];
                oacc[dt] = __builtin_amdgcn_mfma_f32_32x32x16_bf16(
                    vf, pfk, oacc[dt], 0, 0, 0);
            }
        }
        __builtin_amdgcn_s_setprio(0);
    }

    // epilogue: cross-lane l reduction, write f32 partials (no normalize)
    lsum += __shfl_xor(lsum, 32);
    const size_t nO = (size_t)BATCH * NH * SEQ * HD;
    const size_t row = bh * SEQ + (q0 + w * 32 + l31);
    float* ob = opart + (size_t)half * nO + row * HD;
    if (hi == 0) lpart[(size_t)half * ((size_t)BATCH * NH * SEQ) + row] = lsum;
    #pragma unroll
    for (int dt = 0; dt < 2; ++dt) {
        #pragma unroll
        for (int rq = 0; rq < 4; ++rq) {
            f32x4 v;
            v[0] = oacc[dt][rq * 4 + 0];
            v[1] = oacc[dt][rq * 4 + 1];
            v[2] = oacc[dt][rq * 4 + 2];
            v[3] = oacc[dt][rq * 4 + 3];
            *(f32x4*)(ob + dt * 32 + rq * 8 + hi * 4) = v;
        }
    }
}

// combine: ab[b][s][h*64+d] = bf16((O1+O2) / (l1+l2)); 8 elems/thread.
__global__ __launch_bounds__(256) void combine_k(
    const float* __restrict__ opart, const float* __restrict__ lpart,
    unsigned short* __restrict__ ab)
{
    const size_t nO = (size_t)BATCH * NH * SEQ * HD;
    size_t e = ((size_t)blockIdx.x * 256 + threadIdx.x) * 8;
    size_t row = e >> 6;          // bh*SEQ + s
    int d0 = (int)(e & 63);
    int bh = (int)(row >> 12), s = (int)(row & (SEQ - 1));
    int b = bh / NH, h = bh - b * NH;
    float inv = 1.0f / (lpart[row] + lpart[(size_t)BATCH * NH * SEQ + row]);
    f32x4 a0 = *(const f32x4*)(opart + e);
    f32x4 a1 = *(const f32x4*)(opart + e + 4);
    f32x4 b0 = *(const f32x4*)(opart + nO + e);
    f32x4 b1 = *(const f32x4*)(opart + nO + e + 4);
    short8 o;
    #pragma unroll
    for (int j = 0; j < 4; ++j) {
        o[j]     = (short)f2bf((a0[j] + b0[j]) * inv);
        o[4 + j] = (short)f2bf((a1[j] + b1[j]) * inv);
    }
    *(short8*)(ab + ((size_t)(b * SEQ + s)) * D_MODEL + h * HD + d0) = o;
}

extern "C" void kernel_launch(void* const* d_in, const int* in_sizes, int n_in,
                              void* d_out, int out_size, void* d_ws, size_t ws_size,
                              hipStream_t stream)
{
    const float* x  = (const float*)d_in[0];
    const float* Wq = (const float*)d_in[1];
    const float* bq = (const float*)d_in[2];
    const float* Wk = (const float*)d_in[3];
    const float* bk = (const float*)d_in[4];
    const float* Wv = (const float*)d_in[5];
    const float* bv = (const float*)d_in[6];
    const float* Wo = (const float*)d_in[7];
    const float* bo = (const float*)d_in[8];
    float* out = (float*)d_out;

    const size_t n_x  = (size_t)NROWS * D_MODEL;       // == B*NH*SEQ*HD
    const size_t n_w  = (size_t)D_MODEL * D_MODEL;
    const size_t n_l  = (size_t)BATCH * NH * SEQ;
    unsigned short* xb  = (unsigned short*)d_ws;
    unsigned short* wt  = xb + n_x;
    unsigned short* qb  = wt + 4 * n_w;
    unsigned short* kb  = qb + n_x;
    unsigned short* vtb = kb + n_x;
    unsigned short* ab  = vtb + n_x;
    float* opart = (float*)(ab + n_x);                 // [2][n_x] f32
    float* lpart = opart + 2 * n_x;                    // [2][n_l] f32
    const size_t need_split =
        ((size_t)5 * n_x + 4 * n_w) * sizeof(unsigned short)
        + (2 * n_x + 2 * n_l) * sizeof(float);
    if (ws_size < need_split) return;   // R4 measured: harness ws suffices

    convert_x_k<<<dim3((int)(n_x / 2048)), 256, 0, stream>>>(x, xb);
    convert_wt_k<<<dim3(12, 12, 4), 256, 0, stream>>>(Wq, Wk, Wv, Wo, wt);
    qkv_mfma_k<<<dim3(NROWS / 128, D_MODEL / 64, 3), 256, 0, stream>>>(
        xb, wt, bq, bk, bv, qb, kb, vtb);
    flash_split_k<<<dim3(SEQ / 128, NH, BATCH * 2), 256, 0, stream>>>(
        qb, kb, vtb, opart, lpart);
    combine_k<<<dim3((int)(n_x / 2048)), 256, 0, stream>>>(opart, lpart, ab);
    out_mfma_k<<<dim3(NROWS / 128, D_MODEL / 64), 256, 0, stream>>>(
        ab, wt + 3 * n_w, bo, out);
}

// Round 6
// 295.603 us; speedup vs baseline: 2.0360x; 1.0666x over previous
//
#include <hip/hip_runtime.h>
#include <hip/hip_bf16.h>
#include <math.h>

#define D_MODEL 768
#define NH 12
#define HD 64
#define BATCH 2
#define SEQ 4096
#define NROWS (BATCH * SEQ)   // 8192

#define QSCALE 0.18033688011112042f   // 0.125 * log2(e): softmax via exp2

typedef __attribute__((ext_vector_type(8))) short short8;
typedef __attribute__((ext_vector_type(4))) short short4v;
typedef __attribute__((ext_vector_type(4))) float f32x4;
typedef __attribute__((ext_vector_type(16))) float f32x16;
typedef __attribute__((ext_vector_type(4))) unsigned int uint4v;

__device__ inline unsigned short f2bf(float f) {
    __hip_bfloat16 h = __float2bfloat16(f);   // RNE
    return *reinterpret_cast<unsigned short*>(&h);
}

// packed f32x2 -> bf16x2 (RNE), one VALU op
__device__ __forceinline__ unsigned int cvtpk_bf16(float lo, float hi) {
    unsigned int d;
    asm("v_cvt_pk_bf16_f32 %0, %1, %2" : "=v"(d) : "v"(lo), "v"(hi));
    return d;
}

__device__ __forceinline__ short8 u4_as_s8(uint4v u) {
    return *reinterpret_cast<short8*>(&u);
}

// async global->LDS DMA, 16 B per lane; LDS dest is wave-uniform base + lane*16
__device__ __forceinline__ void async_ld16(const unsigned short* g, unsigned short* l) {
    __builtin_amdgcn_global_load_lds(
        (const __attribute__((address_space(1))) void*)g,
        (__attribute__((address_space(3))) void*)l, 16, 0, 0);
}

// ---------------------------------------------------------------------------
// x fp32 -> bf16 (same layout). 8 elems/thread.
// ---------------------------------------------------------------------------
__global__ __launch_bounds__(256) void convert_x_k(
    const float* __restrict__ x, unsigned short* __restrict__ xb)
{
    size_t i = ((size_t)blockIdx.x * 256 + threadIdx.x) * 8;
    float4 a = *(const float4*)(x + i);
    float4 b = *(const float4*)(x + i + 4);
    short8 o;
    o[0] = (short)f2bf(a.x); o[1] = (short)f2bf(a.y);
    o[2] = (short)f2bf(a.z); o[3] = (short)f2bf(a.w);
    o[4] = (short)f2bf(b.x); o[5] = (short)f2bf(b.y);
    o[6] = (short)f2bf(b.z); o[7] = (short)f2bf(b.w);
    *(short8*)(xb + i) = o;
}

// ---------------------------------------------------------------------------
// W fp32 [768][768] -> Wt bf16 [768][768] TRANSPOSED (Wt[n][k] = W[k][n]).
// ---------------------------------------------------------------------------
__global__ __launch_bounds__(256) void convert_wt_k(
    const float* __restrict__ Wq, const float* __restrict__ Wk,
    const float* __restrict__ Wv, const float* __restrict__ Wo,
    unsigned short* __restrict__ wt)
{
    const float* W = (blockIdx.z == 0) ? Wq : (blockIdx.z == 1) ? Wk
                   : (blockIdx.z == 2) ? Wv : Wo;
    unsigned short* dst = wt + (size_t)blockIdx.z * D_MODEL * D_MODEL;
    __shared__ float tile[64][65];
    const int k0 = blockIdx.x * 64, n0 = blockIdx.y * 64;
    const int t = threadIdx.x;
    const int r = t >> 2, seg = t & 3;
    const float* src = W + (size_t)(k0 + r) * D_MODEL + n0 + seg * 16;
    #pragma unroll
    for (int i = 0; i < 4; ++i) {
        float4 v = *(const float4*)(src + i * 4);
        tile[r][seg * 16 + i * 4 + 0] = v.x;
        tile[r][seg * 16 + i * 4 + 1] = v.y;
        tile[r][seg * 16 + i * 4 + 2] = v.z;
        tile[r][seg * 16 + i * 4 + 3] = v.w;
    }
    __syncthreads();
    unsigned short* d = dst + (size_t)(n0 + r) * D_MODEL + k0 + seg * 16;
    short8 o0, o1;
    #pragma unroll
    for (int j = 0; j < 8; ++j) o0[j] = (short)f2bf(tile[seg * 16 + j][r]);
    #pragma unroll
    for (int j = 0; j < 8; ++j) o1[j] = (short)f2bf(tile[seg * 16 + 8 + j][r]);
    *(short8*)(d) = o0;
    *(short8*)(d + 8) = o1;
}

// ---------------------------------------------------------------------------
// GEMM staging/compute macros (static LDS arrays only — no LDS pointers
// through functions; R4 showed that collapses to flat ops).
// ---------------------------------------------------------------------------
#define GEMM_STAGE(AS, BS, APTR, BPTR, KK)                                   \
    {                                                                        \
        _Pragma("unroll")                                                    \
        for (int j = 0; j < 4; ++j) {                                        \
            int c = (w * 4 + j) * 64 + lane;                                 \
            async_ld16(APTR + (size_t)(r0 + (c >> 3)) * D_MODEL + (KK) + (c & 7) * 8, \
                       &AS[0][0] + (size_t)c * 8);                           \
        }                                                                    \
        _Pragma("unroll")                                                    \
        for (int j = 0; j < 2; ++j) {                                        \
            int c = (w * 2 + j) * 64 + lane;                                 \
            async_ld16(BPTR + (size_t)(c0 + (c >> 3)) * D_MODEL + (KK) + (c & 7) * 8, \
                       &BS[0][0] + (size_t)c * 8);                           \
        }                                                                    \
    }

#define GEMM_COMPUTE(AS, BS)                                                 \
    {                                                                        \
        _Pragma("unroll")                                                    \
        for (int ks = 0; ks < 2; ++ks) {                                     \
            short8 af[2], bf[4];                                             \
            af[0] = *(const short8*)&AS[w * 32 + col][ks * 32 + quad * 8];   \
            af[1] = *(const short8*)&AS[w * 32 + 16 + col][ks * 32 + quad * 8]; \
            _Pragma("unroll")                                                \
            for (int nt = 0; nt < 4; ++nt)                                   \
                bf[nt] = *(const short8*)&BS[nt * 16 + col][ks * 32 + quad * 8]; \
            _Pragma("unroll")                                                \
            for (int mt = 0; mt < 2; ++mt)                                   \
                _Pragma("unroll")                                            \
                for (int nt = 0; nt < 4; ++nt)                               \
                    acc[mt][nt] = __builtin_amdgcn_mfma_f32_16x16x32_bf16(   \
                        af[mt], bf[nt], acc[mt][nt], 0, 0, 0);               \
        }                                                                    \
    }

// ---------------------------------------------------------------------------
// QKV projection, bf16 MFMA 16x16x32, M=128 x N=64 tile, BK=64.
// R12: 2-phase pipeline (T3 minimum form): STAGE(t+1) issued BEFORE
// compute(t); ONE drain-barrier per K-step (was 2). Double-buffered LDS
// (48 KB), even/odd steps unrolled so all LDS indices are static.
// ---------------------------------------------------------------------------
__global__ __launch_bounds__(256) void qkv_mfma_k(
    const unsigned short* __restrict__ xb,
    const unsigned short* __restrict__ wt,
    const float* __restrict__ bq, const float* __restrict__ bk,
    const float* __restrict__ bv,
    unsigned short* __restrict__ qb,         // [B,H,S,64] (pre-scaled)
    unsigned short* __restrict__ kb,         // [B,H,S,64]
    unsigned short* __restrict__ vtb)        // [B,H,64,S]
{
    __shared__ unsigned short As0[128][64], As1[128][64];
    __shared__ unsigned short Bs0[64][64],  Bs1[64][64];
    const int z = blockIdx.z;
    const unsigned short* Wt = wt + (size_t)z * D_MODEL * D_MODEL;
    const float* bias = (z == 0) ? bq : (z == 1) ? bk : bv;
    const int t = threadIdx.x;
    const int w = t >> 6, lane = t & 63, quad = lane >> 4, col = lane & 15;
    const int r0 = blockIdx.x * 128;
    const int c0 = blockIdx.y * 64;

    f32x4 acc[2][4] = {};

    GEMM_STAGE(As0, Bs0, xb, Wt, 0);
    __syncthreads();   // prologue drain (compiler emits vmcnt(0) before barrier)
    #pragma unroll
    for (int kp = 0; kp < 6; ++kp) {
        // even step: compute buf0 @ kk=128*kp, stage buf1 @ kk+64
        GEMM_STAGE(As1, Bs1, xb, Wt, kp * 128 + 64);
        GEMM_COMPUTE(As0, Bs0);
        __syncthreads();   // buf1 DMA drained; buf0 reads complete
        // odd step: compute buf1, stage buf0 @ kk=128*kp+128
        if (kp < 5) GEMM_STAGE(As0, Bs0, xb, Wt, kp * 128 + 128);
        GEMM_COMPUTE(As1, Bs1);
        __syncthreads();
    }

    const int h = blockIdx.y;
    #pragma unroll
    for (int nt = 0; nt < 4; ++nt) {
        const float bv_ = bias[c0 + nt * 16 + col];
        const int hd = nt * 16 + col;
        #pragma unroll
        for (int mt = 0; mt < 2; ++mt) {
            #pragma unroll
            for (int reg = 0; reg < 4; ++reg) {
                int r = r0 + w * 32 + mt * 16 + quad * 4 + reg;
                int b = r >> 12, s = r & (SEQ - 1);
                float val = acc[mt][nt][reg] + bv_;
                size_t bh = (size_t)(b * NH + h);
                if (z == 0)
                    qb[(bh * SEQ + s) * HD + hd] = f2bf(val * QSCALE);
                else if (z == 1)
                    kb[(bh * SEQ + s) * HD + hd] = f2bf(val);
                else
                    vtb[(bh * HD + hd) * SEQ + s] = f2bf(val);
            }
        }
    }
}

// ---------------------------------------------------------------------------
// Output projection: out = ab @ Wo + bo, fp32 out. Same 2-phase structure.
// ---------------------------------------------------------------------------
__global__ __launch_bounds__(256) void out_mfma_k(
    const unsigned short* __restrict__ ab,
    const unsigned short* __restrict__ wot,
    const float* __restrict__ bo,
    float* __restrict__ out)
{
    __shared__ unsigned short As0[128][64], As1[128][64];
    __shared__ unsigned short Bs0[64][64],  Bs1[64][64];
    const int t = threadIdx.x;
    const int w = t >> 6, lane = t & 63, quad = lane >> 4, col = lane & 15;
    const int r0 = blockIdx.x * 128;
    const int c0 = blockIdx.y * 64;

    f32x4 acc[2][4] = {};

    GEMM_STAGE(As0, Bs0, ab, wot, 0);
    __syncthreads();
    #pragma unroll
    for (int kp = 0; kp < 6; ++kp) {
        GEMM_STAGE(As1, Bs1, ab, wot, kp * 128 + 64);
        GEMM_COMPUTE(As0, Bs0);
        __syncthreads();
        if (kp < 5) GEMM_STAGE(As0, Bs0, ab, wot, kp * 128 + 128);
        GEMM_COMPUTE(As1, Bs1);
        __syncthreads();
    }

    #pragma unroll
    for (int nt = 0; nt < 4; ++nt) {
        const float bv_ = bo[c0 + nt * 16 + col];
        #pragma unroll
        for (int mt = 0; mt < 2; ++mt) {
            #pragma unroll
            for (int reg = 0; reg < 4; ++reg) {
                int r = r0 + w * 32 + mt * 16 + quad * 4 + reg;
                out[(size_t)r * D_MODEL + c0 + nt * 16 + col] = acc[mt][nt][reg] + bv_;
            }
        }
    }
}

// register-only helper (proven safe: no LDS params)
__device__ __forceinline__ void softmax_pack(
    const f32x16& s, float& lsum, short8& pf0, short8& pf1)
{
    float p[16];
    #pragma unroll
    for (int r = 0; r < 16; ++r)
        p[r] = __builtin_amdgcn_exp2f(s[r]);
    lsum += (((p[0] + p[1]) + (p[2] + p[3])) + ((p[4] + p[5]) + (p[6] + p[7])))
          + (((p[8] + p[9]) + (p[10] + p[11])) + ((p[12] + p[13]) + (p[14] + p[15])));
    unsigned int c01 = cvtpk_bf16(p[0],  p[1]);
    unsigned int c45 = cvtpk_bf16(p[4],  p[5]);
    unsigned int c23 = cvtpk_bf16(p[2],  p[3]);
    unsigned int c67 = cvtpk_bf16(p[6],  p[7]);
    unsigned int c89 = cvtpk_bf16(p[8],  p[9]);
    unsigned int cCD = cvtpk_bf16(p[12], p[13]);
    unsigned int cAB = cvtpk_bf16(p[10], p[11]);
    unsigned int cEF = cvtpk_bf16(p[14], p[15]);
    auto r0 = __builtin_amdgcn_permlane32_swap((int)c01, (int)c45, false, false);
    auto r1 = __builtin_amdgcn_permlane32_swap((int)c23, (int)c67, false, false);
    auto r2 = __builtin_amdgcn_permlane32_swap((int)c89, (int)cCD, false, false);
    auto r3 = __builtin_amdgcn_permlane32_swap((int)cAB, (int)cEF, false, false);
    uint4v u0, u1;
    u0[0] = (unsigned int)r0[0]; u0[1] = (unsigned int)r1[0];
    u0[2] = (unsigned int)r0[1]; u0[3] = (unsigned int)r1[1];
    u1[0] = (unsigned int)r2[0]; u1[1] = (unsigned int)r3[0];
    u1[2] = (unsigned int)r2[1]; u1[3] = (unsigned int)r3[1];
    pf0 = u4_as_s8(u0);
    pf1 = u4_as_s8(u1);
}

// ---------------------------------------------------------------------------
// Flash attention (R1 structure — measured 137 us; split-K refuted R4/R5:
// VGPR=80 caps 4 blocks/CU so extra blocks don't raise occupancy).
// bf16 MFMA 32x32x16, transposed scores (S^T = K Q^T), fixed-max softmax,
// LDS stride 66. T12 in-register P; T14 prefetch; T5 setprio.
// Block = (b, h, 128-q tile); 4 waves x 32 q; 64-key tiles.
// ---------------------------------------------------------------------------
__global__ __launch_bounds__(256) void flash_mfma_k(
    const unsigned short* __restrict__ qb,   // [B*NH][SEQ][64], pre-scaled
    const unsigned short* __restrict__ kb,   // [B*NH][SEQ][64]
    const unsigned short* __restrict__ vtb,  // [B*NH][64][SEQ]
    unsigned short* __restrict__ ab)         // [B][SEQ][768] bf16
{
    __shared__ unsigned short Ks[64][66];
    __shared__ unsigned short Vts[64][66];

    const int t = threadIdx.x;
    const int w = t >> 6, lane = t & 63;
    const int l31 = lane & 31, hi = lane >> 5;
    const int q0 = blockIdx.x * 128;
    const int h = blockIdx.y, b = blockIdx.z;
    const size_t bh = (size_t)b * NH + h;
    const unsigned short* qg = qb + bh * SEQ * HD;
    const unsigned short* kg = kb + bh * SEQ * HD;
    const unsigned short* vg = vtb + bh * HD * SEQ;

    // persistent Q B-frags: q(n) = q0 + w*32 + l31, hd(k) = ks*16 + hi*8 + j
    short8 qf[4];
    {
        const unsigned short* src = qg + (size_t)(q0 + w * 32 + l31) * HD + hi * 8;
        #pragma unroll
        for (int ks = 0; ks < 4; ++ks)
            qf[ks] = *(const short8*)(src + ks * 16);
    }

    f32x16 oacc[2] = {};   // O^T [dt]: d = dt*32+(reg&3)+8*(reg>>2)+4*hi, q = l31
    float lsum = 0.f;
    const int srow = lane, sseg = w;

    // prologue prefetch: tile kt = 0
    short8 kr0, kr1, vr0, vr1;
    {
        const unsigned short* kp = kg + (size_t)srow * HD + sseg * 16;
        kr0 = *(const short8*)(kp);
        kr1 = *(const short8*)(kp + 8);
        const unsigned short* vp = vg + (size_t)srow * SEQ + sseg * 16;
        vr0 = *(const short8*)(vp);
        vr1 = *(const short8*)(vp + 8);
    }

    for (int kt = 0; kt < SEQ; kt += 64) {
        __syncthreads();   // prior compute done reading LDS
        *(short8*)&Ks[srow][sseg * 16]      = kr0;
        *(short8*)&Ks[srow][sseg * 16 + 8]  = kr1;
        *(short8*)&Vts[srow][sseg * 16]     = vr0;
        *(short8*)&Vts[srow][sseg * 16 + 8] = vr1;
        // T14: issue next tile's loads now; latency hides under compute below
        if (kt + 64 < SEQ) {
            const unsigned short* kp = kg + (size_t)(kt + 64 + srow) * HD + sseg * 16;
            kr0 = *(const short8*)(kp);
            kr1 = *(const short8*)(kp + 8);
            const unsigned short* vp = vg + (size_t)srow * SEQ + kt + 64 + sseg * 16;
            vr0 = *(const short8*)(vp);
            vr1 = *(const short8*)(vp + 8);
        }
        __syncthreads();   // staged tile visible to all waves

        // S^T = K Q^T, one 32x32 tile per kti; softmax + in-register P pack
        short8 pf[4];
        #pragma unroll
        for (int kti = 0; kti < 2; ++kti) {
            f32x16 s = {};
            __builtin_amdgcn_s_setprio(1);
            #pragma unroll
            for (int ks = 0; ks < 4; ++ks) {
                short8 kf = *(const short8*)&Ks[kti * 32 + l31][ks * 16 + hi * 8];
                s = __builtin_amdgcn_mfma_f32_32x32x16_bf16(kf, qf[ks], s, 0, 0, 0);
            }
            __builtin_amdgcn_s_setprio(0);
            softmax_pack(s, lsum, pf[kti * 2 + 0], pf[kti * 2 + 1]);
        }

        // PV: O^T = V^T P   (A = V^T frag from LDS, B = P frag in registers)
        __builtin_amdgcn_s_setprio(1);
        #pragma unroll
        for (int ks = 0; ks < 4; ++ks) {
            short8 pfk = pf[ks];
            #pragma unroll
            for (int dt = 0; dt < 2; ++dt) {
                short8 vf = *(const short8*)&Vts[dt * 32 + l31][ks * 16 + hi * 8];
                oacc[dt] = __builtin_amdgcn_mfma_f32_32x32x16_bf16(
                    vf, pfk, oacc[dt], 0, 0, 0);
            }
        }
        __builtin_amdgcn_s_setprio(0);
    }

    // epilogue: single cross-lane l reduction, normalize, b64 stores
    lsum += __shfl_xor(lsum, 32);
    float inv = 1.0f / lsum;
    int s = q0 + w * 32 + l31;
    unsigned short* dst = ab + ((size_t)b * SEQ + s) * D_MODEL + h * HD;
    #pragma unroll
    for (int dt = 0; dt < 2; ++dt) {
        #pragma unroll
        for (int rq = 0; rq < 4; ++rq) {
            short4v o4;
            o4[0] = (short)f2bf(oacc[dt][rq * 4 + 0] * inv);
            o4[1] = (short)f2bf(oacc[dt][rq * 4 + 1] * inv);
            o4[2] = (short)f2bf(oacc[dt][rq * 4 + 2] * inv);
            o4[3] = (short)f2bf(oacc[dt][rq * 4 + 3] * inv);
            *(short4v*)(dst + dt * 32 + rq * 8 + hi * 4) = o4;
        }
    }
}

extern "C" void kernel_launch(void* const* d_in, const int* in_sizes, int n_in,
                              void* d_out, int out_size, void* d_ws, size_t ws_size,
                              hipStream_t stream)
{
    const float* x  = (const float*)d_in[0];
    const float* Wq = (const float*)d_in[1];
    const float* bq = (const float*)d_in[2];
    const float* Wk = (const float*)d_in[3];
    const float* bk = (const float*)d_in[4];
    const float* Wv = (const float*)d_in[5];
    const float* bv = (const float*)d_in[6];
    const float* Wo = (const float*)d_in[7];
    const float* bo = (const float*)d_in[8];
    float* out = (float*)d_out;

    const size_t n_x  = (size_t)NROWS * D_MODEL;
    const size_t n_w  = (size_t)D_MODEL * D_MODEL;
    unsigned short* xb  = (unsigned short*)d_ws;
    unsigned short* wt  = xb + n_x;
    unsigned short* qb  = wt + 4 * n_w;
    unsigned short* kb  = qb + n_x;
    unsigned short* vtb = kb + n_x;
    unsigned short* ab  = vtb + n_x;
    const size_t need = ((size_t)5 * n_x + 4 * n_w) * sizeof(unsigned short);
    if (ws_size < need) return;

    convert_x_k<<<dim3((int)(n_x / 2048)), 256, 0, stream>>>(x, xb);
    convert_wt_k<<<dim3(12, 12, 4), 256, 0, stream>>>(Wq, Wk, Wv, Wo, wt);
    qkv_mfma_k<<<dim3(NROWS / 128, D_MODEL / 64, 3), 256, 0, stream>>>(
        xb, wt, bq, bk, bv, qb, kb, vtb);
    flash_mfma_k<<<dim3(SEQ / 128, NH, BATCH), 256, 0, stream>>>(qb, kb, vtb, ab);
    out_mfma_k<<<dim3(NROWS / 128, D_MODEL / 64), 256, 0, stream>>>(
        ab, wt + 3 * n_w, bo, out);
}

// Round 7
// 281.545 us; speedup vs baseline: 2.1377x; 1.0499x over previous
//
#include <hip/hip_runtime.h>
#include <hip/hip_bf16.h>
#include <math.h>

#define D_MODEL 768
#define NH 12
#define HD 64
#define BATCH 2
#define SEQ 4096
#define NROWS (BATCH * SEQ)   // 8192

#define QSCALE 0.18033688011112042f   // 0.125 * log2(e): softmax via exp2

typedef __attribute__((ext_vector_type(8))) short short8;
typedef __attribute__((ext_vector_type(4))) short short4v;
typedef __attribute__((ext_vector_type(4))) float f32x4;
typedef __attribute__((ext_vector_type(16))) float f32x16;
typedef __attribute__((ext_vector_type(4))) unsigned int uint4v;

__device__ inline unsigned short f2bf(float f) {
    __hip_bfloat16 h = __float2bfloat16(f);   // RNE
    return *reinterpret_cast<unsigned short*>(&h);
}

// packed f32x2 -> bf16x2 (RNE), one VALU op
__device__ __forceinline__ unsigned int cvtpk_bf16(float lo, float hi) {
    unsigned int d;
    asm("v_cvt_pk_bf16_f32 %0, %1, %2" : "=v"(d) : "v"(lo), "v"(hi));
    return d;
}

__device__ __forceinline__ short8 u4_as_s8(uint4v u) {
    return *reinterpret_cast<short8*>(&u);
}

// async global->LDS DMA, 16 B per lane; LDS dest is wave-uniform base + lane*16
__device__ __forceinline__ void async_ld16(const unsigned short* g, unsigned short* l) {
    __builtin_amdgcn_global_load_lds(
        (const __attribute__((address_space(1))) void*)g,
        (__attribute__((address_space(3))) void*)l, 16, 0, 0);
}

// ---------------------------------------------------------------------------
// x fp32 -> bf16 (same layout). 8 elems/thread.
// ---------------------------------------------------------------------------
__global__ __launch_bounds__(256) void convert_x_k(
    const float* __restrict__ x, unsigned short* __restrict__ xb)
{
    size_t i = ((size_t)blockIdx.x * 256 + threadIdx.x) * 8;
    float4 a = *(const float4*)(x + i);
    float4 b = *(const float4*)(x + i + 4);
    short8 o;
    o[0] = (short)f2bf(a.x); o[1] = (short)f2bf(a.y);
    o[2] = (short)f2bf(a.z); o[3] = (short)f2bf(a.w);
    o[4] = (short)f2bf(b.x); o[5] = (short)f2bf(b.y);
    o[6] = (short)f2bf(b.z); o[7] = (short)f2bf(b.w);
    *(short8*)(xb + i) = o;
}

// ---------------------------------------------------------------------------
// W fp32 [768][768] -> Wt bf16 [768][768] TRANSPOSED (Wt[n][k] = W[k][n]).
// ---------------------------------------------------------------------------
__global__ __launch_bounds__(256) void convert_wt_k(
    const float* __restrict__ Wq, const float* __restrict__ Wk,
    const float* __restrict__ Wv, const float* __restrict__ Wo,
    unsigned short* __restrict__ wt)
{
    const float* W = (blockIdx.z == 0) ? Wq : (blockIdx.z == 1) ? Wk
                   : (blockIdx.z == 2) ? Wv : Wo;
    unsigned short* dst = wt + (size_t)blockIdx.z * D_MODEL * D_MODEL;
    __shared__ float tile[64][65];
    const int k0 = blockIdx.x * 64, n0 = blockIdx.y * 64;
    const int t = threadIdx.x;
    const int r = t >> 2, seg = t & 3;
    const float* src = W + (size_t)(k0 + r) * D_MODEL + n0 + seg * 16;
    #pragma unroll
    for (int i = 0; i < 4; ++i) {
        float4 v = *(const float4*)(src + i * 4);
        tile[r][seg * 16 + i * 4 + 0] = v.x;
        tile[r][seg * 16 + i * 4 + 1] = v.y;
        tile[r][seg * 16 + i * 4 + 2] = v.z;
        tile[r][seg * 16 + i * 4 + 3] = v.w;
    }
    __syncthreads();
    unsigned short* d = dst + (size_t)(n0 + r) * D_MODEL + k0 + seg * 16;
    short8 o0, o1;
    #pragma unroll
    for (int j = 0; j < 8; ++j) o0[j] = (short)f2bf(tile[seg * 16 + j][r]);
    #pragma unroll
    for (int j = 0; j < 8; ++j) o1[j] = (short)f2bf(tile[seg * 16 + 8 + j][r]);
    *(short8*)(d) = o0;
    *(short8*)(d + 8) = o1;
}

// ---------------------------------------------------------------------------
// FUSED QKV projection (R13): one block computes q, k, v for its
// (128-row, 64-col) tile. A staged ONCE per K-step (was 3x across z),
// 48 MFMAs per barrier pair (was 16) -> staging ops and drain stall per
// MFMA cut ~3x. LDS: As 16 KB + 3x Bs 8 KB = 40 KB, single-buffered
// (2 barriers/K-step). launch_bounds(256,3): VGPR cap 170 -> 3 blocks/CU,
// grid 64x12 = 768 = exactly 3/CU.
// Epilogue: q scaled by 0.125*log2e, v written TRANSPOSED [b,h,d,s].
// ---------------------------------------------------------------------------
__global__ __launch_bounds__(256, 3) void qkv_fused_k(
    const unsigned short* __restrict__ xb,
    const unsigned short* __restrict__ wt,   // [3][768][768] (q,k,v transposed)
    const float* __restrict__ bq, const float* __restrict__ bk,
    const float* __restrict__ bv,
    unsigned short* __restrict__ qb,         // [B,H,S,64] (pre-scaled)
    unsigned short* __restrict__ kb,         // [B,H,S,64]
    unsigned short* __restrict__ vtb)        // [B,H,64,S]
{
    __shared__ unsigned short As[128][64];
    __shared__ unsigned short Bs[3][64][64];
    const int t = threadIdx.x;
    const int w = t >> 6, lane = t & 63, quad = lane >> 4, col = lane & 15;
    const int r0 = blockIdx.x * 128;
    const int c0 = blockIdx.y * 64;

    f32x4 acc[3][2][4] = {};

    for (int kk = 0; kk < D_MODEL; kk += 64) {
        __syncthreads();   // prior compute done reading LDS
        // A tile: 128 rows x 64 cols = 1024 chunks of 8 shorts (once!)
        #pragma unroll
        for (int j = 0; j < 4; ++j) {
            int c = (w * 4 + j) * 64 + lane;
            async_ld16(xb + (size_t)(r0 + (c >> 3)) * D_MODEL + kk + (c & 7) * 8,
                       &As[0][0] + (size_t)c * 8);
        }
        // B tiles for q, k, v: 3 x 512 chunks
        #pragma unroll
        for (int z = 0; z < 3; ++z) {
            const unsigned short* Wt = wt + (size_t)z * D_MODEL * D_MODEL;
            #pragma unroll
            for (int j = 0; j < 2; ++j) {
                int c = (w * 2 + j) * 64 + lane;
                async_ld16(Wt + (size_t)(c0 + (c >> 3)) * D_MODEL + kk + (c & 7) * 8,
                           &Bs[z][0][0] + (size_t)c * 8);
            }
        }
        __syncthreads();   // DMA drained by pre-barrier vmcnt(0)
        #pragma unroll
        for (int ks = 0; ks < 2; ++ks) {
            short8 af[2];
            af[0] = *(const short8*)&As[w * 32 + col][ks * 32 + quad * 8];
            af[1] = *(const short8*)&As[w * 32 + 16 + col][ks * 32 + quad * 8];
            #pragma unroll
            for (int z = 0; z < 3; ++z) {
                short8 bf[4];
                #pragma unroll
                for (int nt = 0; nt < 4; ++nt)
                    bf[nt] = *(const short8*)&Bs[z][nt * 16 + col][ks * 32 + quad * 8];
                #pragma unroll
                for (int mt = 0; mt < 2; ++mt)
                    #pragma unroll
                    for (int nt = 0; nt < 4; ++nt)
                        acc[z][mt][nt] = __builtin_amdgcn_mfma_f32_16x16x32_bf16(
                            af[mt], bf[nt], acc[z][mt][nt], 0, 0, 0);
            }
        }
    }

    const int h = blockIdx.y;
    #pragma unroll
    for (int z = 0; z < 3; ++z) {
        const float* bias = (z == 0) ? bq : (z == 1) ? bk : bv;
        #pragma unroll
        for (int nt = 0; nt < 4; ++nt) {
            const float bv_ = bias[c0 + nt * 16 + col];
            const int hd = nt * 16 + col;
            #pragma unroll
            for (int mt = 0; mt < 2; ++mt) {
                #pragma unroll
                for (int reg = 0; reg < 4; ++reg) {
                    int r = r0 + w * 32 + mt * 16 + quad * 4 + reg;
                    int b = r >> 12, s = r & (SEQ - 1);
                    float val = acc[z][mt][nt][reg] + bv_;
                    size_t bh = (size_t)(b * NH + h);
                    if (z == 0)
                        qb[(bh * SEQ + s) * HD + hd] = f2bf(val * QSCALE);
                    else if (z == 1)
                        kb[(bh * SEQ + s) * HD + hd] = f2bf(val);
                    else
                        vtb[(bh * HD + hd) * SEQ + s] = f2bf(val);
                }
            }
        }
    }
}

// ---------------------------------------------------------------------------
// Output projection: out = ab @ Wo + bo, fp32 out. R6 2-phase pipeline.
// ---------------------------------------------------------------------------
#define GEMM_STAGE(AS, BS, APTR, BPTR, KK)                                   \
    {                                                                        \
        _Pragma("unroll")                                                    \
        for (int j = 0; j < 4; ++j) {                                        \
            int c = (w * 4 + j) * 64 + lane;                                 \
            async_ld16(APTR + (size_t)(r0 + (c >> 3)) * D_MODEL + (KK) + (c & 7) * 8, \
                       &AS[0][0] + (size_t)c * 8);                           \
        }                                                                    \
        _Pragma("unroll")                                                    \
        for (int j = 0; j < 2; ++j) {                                        \
            int c = (w * 2 + j) * 64 + lane;                                 \
            async_ld16(BPTR + (size_t)(c0 + (c >> 3)) * D_MODEL + (KK) + (c & 7) * 8, \
                       &BS[0][0] + (size_t)c * 8);                           \
        }                                                                    \
    }

#define GEMM_COMPUTE(AS, BS)                                                 \
    {                                                                        \
        _Pragma("unroll")                                                    \
        for (int ks = 0; ks < 2; ++ks) {                                     \
            short8 af[2], bf[4];                                             \
            af[0] = *(const short8*)&AS[w * 32 + col][ks * 32 + quad * 8];   \
            af[1] = *(const short8*)&AS[w * 32 + 16 + col][ks * 32 + quad * 8]; \
            _Pragma("unroll")                                                \
            for (int nt = 0; nt < 4; ++nt)                                   \
                bf[nt] = *(const short8*)&BS[nt * 16 + col][ks * 32 + quad * 8]; \
            _Pragma("unroll")                                                \
            for (int mt = 0; mt < 2; ++mt)                                   \
                _Pragma("unroll")                                            \
                for (int nt = 0; nt < 4; ++nt)                               \
                    acc[mt][nt] = __builtin_amdgcn_mfma_f32_16x16x32_bf16(   \
                        af[mt], bf[nt], acc[mt][nt], 0, 0, 0);               \
        }                                                                    \
    }

__global__ __launch_bounds__(256) void out_mfma_k(
    const unsigned short* __restrict__ ab,
    const unsigned short* __restrict__ wot,
    const float* __restrict__ bo,
    float* __restrict__ out)
{
    __shared__ unsigned short As0[128][64], As1[128][64];
    __shared__ unsigned short Bs0[64][64],  Bs1[64][64];
    const int t = threadIdx.x;
    const int w = t >> 6, lane = t & 63, quad = lane >> 4, col = lane & 15;
    const int r0 = blockIdx.x * 128;
    const int c0 = blockIdx.y * 64;

    f32x4 acc[2][4] = {};

    GEMM_STAGE(As0, Bs0, ab, wot, 0);
    __syncthreads();
    #pragma unroll
    for (int kp = 0; kp < 6; ++kp) {
        GEMM_STAGE(As1, Bs1, ab, wot, kp * 128 + 64);
        GEMM_COMPUTE(As0, Bs0);
        __syncthreads();
        if (kp < 5) GEMM_STAGE(As0, Bs0, ab, wot, kp * 128 + 128);
        GEMM_COMPUTE(As1, Bs1);
        __syncthreads();
    }

    #pragma unroll
    for (int nt = 0; nt < 4; ++nt) {
        const float bv_ = bo[c0 + nt * 16 + col];
        #pragma unroll
        for (int mt = 0; mt < 2; ++mt) {
            #pragma unroll
            for (int reg = 0; reg < 4; ++reg) {
                int r = r0 + w * 32 + mt * 16 + quad * 4 + reg;
                out[(size_t)r * D_MODEL + c0 + nt * 16 + col] = acc[mt][nt][reg] + bv_;
            }
        }
    }
}

// register-only helper (proven safe: no LDS params)
__device__ __forceinline__ void softmax_pack(
    const f32x16& s, float& lsum, short8& pf0, short8& pf1)
{
    float p[16];
    #pragma unroll
    for (int r = 0; r < 16; ++r)
        p[r] = __builtin_amdgcn_exp2f(s[r]);
    lsum += (((p[0] + p[1]) + (p[2] + p[3])) + ((p[4] + p[5]) + (p[6] + p[7])))
          + (((p[8] + p[9]) + (p[10] + p[11])) + ((p[12] + p[13]) + (p[14] + p[15])));
    unsigned int c01 = cvtpk_bf16(p[0],  p[1]);
    unsigned int c45 = cvtpk_bf16(p[4],  p[5]);
    unsigned int c23 = cvtpk_bf16(p[2],  p[3]);
    unsigned int c67 = cvtpk_bf16(p[6],  p[7]);
    unsigned int c89 = cvtpk_bf16(p[8],  p[9]);
    unsigned int cCD = cvtpk_bf16(p[12], p[13]);
    unsigned int cAB = cvtpk_bf16(p[10], p[11]);
    unsigned int cEF = cvtpk_bf16(p[14], p[15]);
    auto r0 = __builtin_amdgcn_permlane32_swap((int)c01, (int)c45, false, false);
    auto r1 = __builtin_amdgcn_permlane32_swap((int)c23, (int)c67, false, false);
    auto r2 = __builtin_amdgcn_permlane32_swap((int)c89, (int)cCD, false, false);
    auto r3 = __builtin_amdgcn_permlane32_swap((int)cAB, (int)cEF, false, false);
    uint4v u0, u1;
    u0[0] = (unsigned int)r0[0]; u0[1] = (unsigned int)r1[0];
    u0[2] = (unsigned int)r0[1]; u0[3] = (unsigned int)r1[1];
    u1[0] = (unsigned int)r2[0]; u1[1] = (unsigned int)r3[0];
    u1[2] = (unsigned int)r2[1]; u1[3] = (unsigned int)r3[1];
    pf0 = u4_as_s8(u0);
    pf1 = u4_as_s8(u1);
}

// ---------------------------------------------------------------------------
// Flash attention (R1 structure — the measured local optimum; split-K
// refuted R4/R5, thin blocks refuted R3). bf16 MFMA 32x32x16, transposed
// scores, fixed-max softmax, LDS stride 66. T12 + T14 + T5.
// Block = (b, h, 128-q tile); 4 waves x 32 q; 64-key tiles.
// ---------------------------------------------------------------------------
__global__ __launch_bounds__(256) void flash_mfma_k(
    const unsigned short* __restrict__ qb,   // [B*NH][SEQ][64], pre-scaled
    const unsigned short* __restrict__ kb,   // [B*NH][SEQ][64]
    const unsigned short* __restrict__ vtb,  // [B*NH][64][SEQ]
    unsigned short* __restrict__ ab)         // [B][SEQ][768] bf16
{
    __shared__ unsigned short Ks[64][66];
    __shared__ unsigned short Vts[64][66];

    const int t = threadIdx.x;
    const int w = t >> 6, lane = t & 63;
    const int l31 = lane & 31, hi = lane >> 5;
    const int q0 = blockIdx.x * 128;
    const int h = blockIdx.y, b = blockIdx.z;
    const size_t bh = (size_t)b * NH + h;
    const unsigned short* qg = qb + bh * SEQ * HD;
    const unsigned short* kg = kb + bh * SEQ * HD;
    const unsigned short* vg = vtb + bh * HD * SEQ;

    // persistent Q B-frags: q(n) = q0 + w*32 + l31, hd(k) = ks*16 + hi*8 + j
    short8 qf[4];
    {
        const unsigned short* src = qg + (size_t)(q0 + w * 32 + l31) * HD + hi * 8;
        #pragma unroll
        for (int ks = 0; ks < 4; ++ks)
            qf[ks] = *(const short8*)(src + ks * 16);
    }

    f32x16 oacc[2] = {};   // O^T [dt]: d = dt*32+(reg&3)+8*(reg>>2)+4*hi, q = l31
    float lsum = 0.f;
    const int srow = lane, sseg = w;

    // prologue prefetch: tile kt = 0
    short8 kr0, kr1, vr0, vr1;
    {
        const unsigned short* kp = kg + (size_t)srow * HD + sseg * 16;
        kr0 = *(const short8*)(kp);
        kr1 = *(const short8*)(kp + 8);
        const unsigned short* vp = vg + (size_t)srow * SEQ + sseg * 16;
        vr0 = *(const short8*)(vp);
        vr1 = *(const short8*)(vp + 8);
    }

    for (int kt = 0; kt < SEQ; kt += 64) {
        __syncthreads();   // prior compute done reading LDS
        *(short8*)&Ks[srow][sseg * 16]      = kr0;
        *(short8*)&Ks[srow][sseg * 16 + 8]  = kr1;
        *(short8*)&Vts[srow][sseg * 16]     = vr0;
        *(short8*)&Vts[srow][sseg * 16 + 8] = vr1;
        // T14: issue next tile's loads now; latency hides under compute below
        if (kt + 64 < SEQ) {
            const unsigned short* kp = kg + (size_t)(kt + 64 + srow) * HD + sseg * 16;
            kr0 = *(const short8*)(kp);
            kr1 = *(const short8*)(kp + 8);
            const unsigned short* vp = vg + (size_t)srow * SEQ + kt + 64 + sseg * 16;
            vr0 = *(const short8*)(vp);
            vr1 = *(const short8*)(vp + 8);
        }
        __syncthreads();   // staged tile visible to all waves

        // S^T = K Q^T, one 32x32 tile per kti; softmax + in-register P pack
        short8 pf[4];
        #pragma unroll
        for (int kti = 0; kti < 2; ++kti) {
            f32x16 s = {};
            __builtin_amdgcn_s_setprio(1);
            #pragma unroll
            for (int ks = 0; ks < 4; ++ks) {
                short8 kf = *(const short8*)&Ks[kti * 32 + l31][ks * 16 + hi * 8];
                s = __builtin_amdgcn_mfma_f32_32x32x16_bf16(kf, qf[ks], s, 0, 0, 0);
            }
            __builtin_amdgcn_s_setprio(0);
            softmax_pack(s, lsum, pf[kti * 2 + 0], pf[kti * 2 + 1]);
        }

        // PV: O^T = V^T P   (A = V^T frag from LDS, B = P frag in registers)
        __builtin_amdgcn_s_setprio(1);
        #pragma unroll
        for (int ks = 0; ks < 4; ++ks) {
            short8 pfk = pf[ks];
            #pragma unroll
            for (int dt = 0; dt < 2; ++dt) {
                short8 vf = *(const short8*)&Vts[dt * 32 + l31][ks * 16 + hi * 8];
                oacc[dt] = __builtin_amdgcn_mfma_f32_32x32x16_bf16(
                    vf, pfk, oacc[dt], 0, 0, 0);
            }
        }
        __builtin_amdgcn_s_setprio(0);
    }

    // epilogue: single cross-lane l reduction, normalize, b64 stores
    lsum += __shfl_xor(lsum, 32);
    float inv = 1.0f / lsum;
    int s = q0 + w * 32 + l31;
    unsigned short* dst = ab + ((size_t)b * SEQ + s) * D_MODEL + h * HD;
    #pragma unroll
    for (int dt = 0; dt < 2; ++dt) {
        #pragma unroll
        for (int rq = 0; rq < 4; ++rq) {
            short4v o4;
            o4[0] = (short)f2bf(oacc[dt][rq * 4 + 0] * inv);
            o4[1] = (short)f2bf(oacc[dt][rq * 4 + 1] * inv);
            o4[2] = (short)f2bf(oacc[dt][rq * 4 + 2] * inv);
            o4[3] = (short)f2bf(oacc[dt][rq * 4 + 3] * inv);
            *(short4v*)(dst + dt * 32 + rq * 8 + hi * 4) = o4;
        }
    }
}

extern "C" void kernel_launch(void* const* d_in, const int* in_sizes, int n_in,
                              void* d_out, int out_size, void* d_ws, size_t ws_size,
                              hipStream_t stream)
{
    const float* x  = (const float*)d_in[0];
    const float* Wq = (const float*)d_in[1];
    const float* bq = (const float*)d_in[2];
    const float* Wk = (const float*)d_in[3];
    const float* bk = (const float*)d_in[4];
    const float* Wv = (const float*)d_in[5];
    const float* bv = (const float*)d_in[6];
    const float* Wo = (const float*)d_in[7];
    const float* bo = (const float*)d_in[8];
    float* out = (float*)d_out;

    const size_t n_x  = (size_t)NROWS * D_MODEL;
    const size_t n_w  = (size_t)D_MODEL * D_MODEL;
    unsigned short* xb  = (unsigned short*)d_ws;
    unsigned short* wt  = xb + n_x;
    unsigned short* qb  = wt + 4 * n_w;
    unsigned short* kb  = qb + n_x;
    unsigned short* vtb = kb + n_x;
    unsigned short* ab  = vtb + n_x;
    const size_t need = ((size_t)5 * n_x + 4 * n_w) * sizeof(unsigned short);
    if (ws_size < need) return;

    convert_x_k<<<dim3((int)(n_x / 2048)), 256, 0, stream>>>(x, xb);
    convert_wt_k<<<dim3(12, 12, 4), 256, 0, stream>>>(Wq, Wk, Wv, Wo, wt);
    qkv_fused_k<<<dim3(NROWS / 128, D_MODEL / 64), 256, 0, stream>>>(
        xb, wt, bq, bk, bv, qb, kb, vtb);
    flash_mfma_k<<<dim3(SEQ / 128, NH, BATCH), 256, 0, stream>>>(qb, kb, vtb, ab);
    out_mfma_k<<<dim3(NROWS / 128, D_MODEL / 64), 256, 0, stream>>>(
        ab, wt + 3 * n_w, bo, out);
}